// Round 7
// baseline (17450.333 us; speedup 1.0000x reference)
//
#include <hip/hip_runtime.h>
#include <math.h>

#define D 512
#define THRESH 0.5f
#define NMAX 8192
#define TOPK 64
#define INFI 0x7fffffff

typedef short bhalf8 __attribute__((ext_vector_type(8)));
typedef float f32x4 __attribute__((ext_vector_type(4)));

__global__ void k_init(int* dn, int n) { *dn = n; }

// fused: norms + fp32->bf16 (RNE). One block (128 thr) per row.
__global__ void k_prep(const float* __restrict__ E, float* __restrict__ norms,
                       unsigned short* __restrict__ H, const int* __restrict__ dn) {
    int n = *dn;
    int row = blockIdx.x;
    if (row >= n) return;
    int t = threadIdx.x; // 0..127
    float4 v = ((const float4*)(E + (size_t)row * D))[t];
    float s = v.x * v.x + v.y * v.y + v.z * v.z + v.w * v.w;
    #pragma unroll
    for (int o = 32; o > 0; o >>= 1) s += __shfl_down(s, o, 64);
    __shared__ float ls[2];
    if ((t & 63) == 0) ls[t >> 6] = s;
    float f[4] = {v.x, v.y, v.z, v.w};
    unsigned short r[4];
    #pragma unroll
    for (int u = 0; u < 4; ++u) {
        unsigned int b = __float_as_uint(f[u]);
        r[u] = (unsigned short)((b + 0x7FFFu + ((b >> 16) & 1u)) >> 16);
    }
    uint2 packed;
    packed.x = (unsigned)r[0] | ((unsigned)r[1] << 16);
    packed.y = (unsigned)r[2] | ((unsigned)r[3] << 16);
    *(uint2*)(H + (size_t)row * D + t * 4) = packed;
    __syncthreads();
    if (t == 0) norms[row] = fmaxf(sqrtf(ls[0] + ls[1]), 1e-8f);
}

// sim tile via bf16 MFMA: 128x128 block tile, 4 waves (2x2), BK=64, K=512.
#define LDSTRIDE 72
__global__ void __launch_bounds__(256) k_mfma_sim(
    const unsigned short* __restrict__ H, const float* __restrict__ norms,
    float* __restrict__ sim, int tile_start, int TR, int simStride,
    const int* __restrict__ dn)
{
    int n = *dn;
    if (tile_start >= n) return;
    int row0 = tile_start + blockIdx.y * 128;
    int col0 = blockIdx.x * 128;
    if (row0 >= n || col0 >= n) return;
    if (col0 + 128 <= row0 + 1) return;     // triangle skip

    __shared__ unsigned short As[128 * LDSTRIDE];
    __shared__ unsigned short Bs[128 * LDSTRIDE];
    int tid = threadIdx.x;
    int lane = tid & 63;
    int wave = tid >> 6;
    int wr = wave >> 1;
    int wc = wave & 1;
    int krow = lane & 15;
    int kgrp = (lane >> 4) * 8;

    f32x4 acc[4][4];
    #pragma unroll
    for (int m = 0; m < 4; ++m)
        #pragma unroll
        for (int t = 0; t < 4; ++t)
            acc[m][t] = (f32x4){0.f, 0.f, 0.f, 0.f};

    for (int k0 = 0; k0 < D; k0 += 64) {
        #pragma unroll
        for (int it = 0; it < 4; ++it) {
            int c  = tid + it * 256;
            int rr = c >> 3;
            int cc = c & 7;
            uint4 va = make_uint4(0, 0, 0, 0);
            int gra = row0 + rr;
            if (gra < n) va = *(const uint4*)(H + (size_t)gra * D + k0 + cc * 8);
            *(uint4*)&As[rr * LDSTRIDE + cc * 8] = va;
            uint4 vb = make_uint4(0, 0, 0, 0);
            int grb = col0 + rr;
            if (grb < n) vb = *(const uint4*)(H + (size_t)grb * D + k0 + cc * 8);
            *(uint4*)&Bs[rr * LDSTRIDE + cc * 8] = vb;
        }
        __syncthreads();
        #pragma unroll
        for (int kk = 0; kk < 64; kk += 32) {
            bhalf8 a[4], b[4];
            #pragma unroll
            for (int m = 0; m < 4; ++m)
                a[m] = *(const bhalf8*)&As[(wr * 64 + m * 16 + krow) * LDSTRIDE + kk + kgrp];
            #pragma unroll
            for (int t = 0; t < 4; ++t)
                b[t] = *(const bhalf8*)&Bs[(wc * 64 + t * 16 + krow) * LDSTRIDE + kk + kgrp];
            #pragma unroll
            for (int m = 0; m < 4; ++m)
                #pragma unroll
                for (int t = 0; t < 4; ++t)
                    acc[m][t] = __builtin_amdgcn_mfma_f32_16x16x32_bf16(a[m], b[t], acc[m][t], 0, 0, 0);
        }
        __syncthreads();
    }

    int fcol = lane & 15;
    int frow = (lane >> 4) * 4;
    #pragma unroll
    for (int m = 0; m < 4; ++m) {
        #pragma unroll
        for (int t = 0; t < 4; ++t) {
            #pragma unroll
            for (int v = 0; v < 4; ++v) {
                int gr = row0 + wr * 64 + m * 16 + frow + v;
                int gc = col0 + wc * 64 + t * 16 + fcol;
                if (gr < n && gc < n)
                    sim[(size_t)(gr - tile_start) * simStride + gc] =
                        acc[m][t][v] / (norms[gr] * norms[gc]);
            }
        }
    }
}

// per-row exact top-64 (val desc, idx asc) among j>i. One wave per row.
__global__ void __launch_bounds__(64) k_topk(
    const float* __restrict__ sim, int tile_start, int TR, int simStride,
    uint2* __restrict__ tkP, int* __restrict__ needFix,
    const int* __restrict__ dn)
{
    int n = *dn;
    int r = blockIdx.x;
    int i = tile_start + r;
    if (r >= TR || i >= n) return;
    int lane = threadIdx.x;
    const float* srow = sim + (size_t)r * simStride;

    float v[8]; int id[8];
    #pragma unroll
    for (int u = 0; u < 8; ++u) { v[u] = -INFINITY; id[u] = INFI; }
    float ovV = -INFINITY; int ovI = INFI;

    for (int j = i + 1 + lane; j < n; j += 64) {
        float x = srow[j];
        if (x > v[7] || (x == v[7] && j < id[7])) {
            if (v[7] > ovV || (v[7] == ovV && id[7] < ovI)) { ovV = v[7]; ovI = id[7]; }
            int p = 7;
            #pragma unroll
            for (int u = 6; u >= 0; --u) {
                bool mv = (x > v[u]) || (x == v[u] && j < id[u]);
                if (mv) { v[u + 1] = v[u]; id[u + 1] = id[u]; p = u; }
            }
            v[p] = x; id[p] = j;
        } else {
            if (x > ovV || (x == ovV && j < ovI)) { ovV = x; ovI = j; }
        }
    }

    int pos = 0;
    float myV = -INFINITY; int myI = INFI;
    for (int k = 0; k < TOPK; ++k) {
        float hv = (pos < 8) ? v[pos] : -INFINITY;
        int   hi = (pos < 8) ? id[pos] : INFI;
        float bv = hv; int bi = hi;
        #pragma unroll
        for (int o = 1; o < 64; o <<= 1) {
            float xv = __shfl_xor(bv, o, 64);
            int   xi = __shfl_xor(bi, o, 64);
            if (xv > bv || (xv == bv && xi < bi)) { bv = xv; bi = xi; }
        }
        if (pos < 8 && hv == bv && hi == bi) pos++;
        if (k == lane) { myV = bv; myI = bi; }
    }
    tkP[(size_t)i * TOPK + lane] = make_uint2(__float_as_uint(myV), (unsigned)myI);

    float v64 = __shfl(myV, 63, 64);
    int   i64 = __shfl(myI, 63, 64);
    float oV = ovV; int oI = ovI;
    #pragma unroll
    for (int o = 1; o < 64; o <<= 1) {
        float xv = __shfl_xor(oV, o, 64);
        int   xi = __shfl_xor(oI, o, 64);
        if (xv > oV || (xv == oV && xi < oI)) { oV = xv; oI = xi; }
    }
    int bad = (oV > v64) || (oV == v64 && oI < i64);
    if (lane == 0) needFix[i] = bad;
}

// rare exact redo: per-lane top-64 lists in LDS (unconditionally exact)
__global__ void __launch_bounds__(64) k_topkfix(
    const float* __restrict__ sim, int tile_start, int TR, int simStride,
    uint2* __restrict__ tkP, const int* __restrict__ needFix,
    const int* __restrict__ dn)
{
    int n = *dn;
    int r = blockIdx.x;
    int i = tile_start + r;
    if (r >= TR || i >= n) return;
    if (!needFix[i]) return;
    int lane = threadIdx.x;
    __shared__ float lv[64][TOPK];
    __shared__ int   li[64][TOPK];
    for (int u = 0; u < TOPK; ++u) { lv[lane][u] = -INFINITY; li[lane][u] = INFI; }
    const float* srow = sim + (size_t)r * simStride;
    for (int j = i + 1 + lane; j < n; j += 64) {
        float x = srow[j];
        float wv = lv[lane][TOPK - 1]; int wi = li[lane][TOPK - 1];
        if (x > wv || (x == wv && j < wi)) {
            int p = TOPK - 1;
            for (int u = TOPK - 2; u >= 0; --u) {
                float uv = lv[lane][u]; int ui = li[lane][u];
                if (x > uv || (x == uv && j < ui)) { lv[lane][u + 1] = uv; li[lane][u + 1] = ui; p = u; }
                else break;
            }
            lv[lane][p] = x; li[lane][p] = j;
        }
    }
    int pos = 0;
    float myV = -INFINITY; int myI = INFI;
    for (int k = 0; k < TOPK; ++k) {
        float hv = (pos < TOPK) ? lv[lane][pos] : -INFINITY;
        int   hi = (pos < TOPK) ? li[lane][pos] : INFI;
        float bv = hv; int bi = hi;
        #pragma unroll
        for (int o = 1; o < 64; o <<= 1) {
            float xv = __shfl_xor(bv, o, 64);
            int   xi = __shfl_xor(bi, o, 64);
            if (xv > bv || (xv == bv && xi < bi)) { bv = xv; bi = xi; }
        }
        if (pos < TOPK && hv == bv && hi == bi) pos++;
        if (k == lane) { myV = bv; myI = bi; }
    }
    tkP[(size_t)i * TOPK + lane] = make_uint2(__float_as_uint(myV), (unsigned)myI);
}

// dot-product fallback (only used when sim matrix is tiled / not fully resident)
// lm64 layout: word w (global bits [w*64,(w+1)*64)) lives at lm64[(w>>1)+((w&1)<<6)]
__device__ __attribute__((noinline)) void exact_fallback(
    int r, int n, int lane, const float* __restrict__ E,
    const float* __restrict__ norms, const unsigned long long* lm64,
    float& obv, int& obj)
{
    float ni = norms[r];
    float4 e0 = *(const float4*)(E + (size_t)r * D + lane * 8);
    float4 e1 = *(const float4*)(E + (size_t)r * D + lane * 8 + 4);
    float bbv = -INFINITY; int bbj = INFI;
    int w0 = (r + 1) >> 6, wN = (n + 63) >> 6;
    for (int ww = w0; ww < wN; ++ww) {
        unsigned long long um = ~lm64[(ww >> 1) + ((ww & 1) << 6)];
        if (ww == (r >> 6)) um &= (~0ull) << ((r & 63) + 1);
        int over = (ww << 6) + 64 - n;
        if (over > 0) um &= (over >= 64) ? 0ull : ((~0ull) >> over);
        while (um) {
            int b = __builtin_ctzll(um);
            um &= um - 1;
            int jj = (ww << 6) + b;
            float4 a0 = *(const float4*)(E + (size_t)jj * D + lane * 8);
            float4 a1 = *(const float4*)(E + (size_t)jj * D + lane * 8 + 4);
            float s = e0.x * a0.x + e0.y * a0.y + e0.z * a0.z + e0.w * a0.w
                    + e1.x * a1.x + e1.y * a1.y + e1.z * a1.z + e1.w * a1.w;
            #pragma unroll
            for (int o = 1; o < 64; o <<= 1) s += __shfl_xor(s, o, 64);
            float sv = s / (ni * norms[jj]);
            if (sv > bbv || (sv == bbv && jj < bbj)) { bbv = sv; bbj = jj; }
        }
    }
    obv = bbv; obj = bbj;
}

// greedy scan, one wave. Register merged-bitmask (128 bits/lane).
// Batches of 8 rows, loads one batch ahead. Fallback (candidates exhausted)
// = masked lex-argmax directly over the precomputed sim row (coalesced).
__global__ void __launch_bounds__(64) k_scan6(
    const uint2* __restrict__ tkP,
    const float* __restrict__ E, const float* __restrict__ norms,
    const float* __restrict__ sim, int simStride, int simOk,
    int* __restrict__ partner, int* __restrict__ srcIdx,
    int* __restrict__ dn)
{
    int n = *dn;
    int lane = threadIdx.x;

    unsigned long long m0 = 0ull, m1 = 0ull;     // merged (leader or consumed)
    unsigned long long cm0 = 0ull, cm1 = 0ull;   // consumed-as-j only
    __shared__ unsigned long long lm64[128];     // [lane]=m0, [64+lane]=m1

    int nextStart = 0;
    const uint2 SENT = make_uint2(0xFF800000u, (unsigned)INFI);

#define DECL8(P, C) int P##0=INFI,P##1=INFI,P##2=INFI,P##3=INFI,P##4=INFI,P##5=INFI,P##6=INFI,P##7=INFI; \
                    uint2 C##0=SENT,C##1=SENT,C##2=SENT,C##3=SENT,C##4=SENT,C##5=SENT,C##6=SENT,C##7=SENT;

#define BUILD(P, C) do {                                                        \
    P##0=INFI;P##1=INFI;P##2=INFI;P##3=INFI;P##4=INFI;P##5=INFI;P##6=INFI;P##7=INFI; \
    int base_ = lane << 7;                                                      \
    unsigned long long u0_ = ~m0, u1_ = ~m1;                                    \
    long long k_ = (long long)nextStart - base_;                                \
    if (k_ > 0) {                                                               \
        if (k_ >= 128) { u0_ = 0ull; u1_ = 0ull; }                              \
        else if (k_ >= 64) { u0_ = 0ull; if (k_ > 64) u1_ &= (~0ull) << (int)(k_ - 64); } \
        else u0_ &= (~0ull) << (int)k_;                                         \
    }                                                                           \
    int kn_ = n - base_;                                                        \
    if (kn_ <= 0) { u0_ = 0ull; u1_ = 0ull; }                                   \
    else if (kn_ < 64) { u0_ &= (~0ull) >> (64 - kn_); u1_ = 0ull; }            \
    else if (kn_ < 128) { u1_ = (kn_ == 64) ? 0ull : (u1_ & ((~0ull) >> (128 - kn_))); } \
    unsigned long long balv_ = __ballot((u0_ | u1_) != 0ull);                   \
    int got_ = 0, lastSel_ = -1;                                                \
    while (got_ < 8 && balv_) {                                                 \
        int L_ = __builtin_ctzll(balv_); balv_ &= balv_ - 1;                    \
        unsigned long long w0_ = __shfl(u0_, L_, 64);                           \
        unsigned long long w1_ = __shfl(u1_, L_, 64);                           \
        int bs_ = L_ << 7;                                                      \
        while (w0_ && got_ < 8) { int b_ = __builtin_ctzll(w0_); w0_ &= w0_-1;  \
            int v_ = bs_ + b_; lastSel_ = v_; SETSEL(P, got_, v_); got_++; }    \
        while (w1_ && got_ < 8) { int b_ = __builtin_ctzll(w1_); w1_ &= w1_-1;  \
            int v_ = bs_ + 64 + b_; lastSel_ = v_; SETSEL(P, got_, v_); got_++; } \
    }                                                                           \
    nextStart = (got_ > 0) ? (lastSel_ + 1) : n;                                \
    C##0 = (P##0 < n) ? tkP[(size_t)P##0 * TOPK + lane] : SENT;                 \
    C##1 = (P##1 < n) ? tkP[(size_t)P##1 * TOPK + lane] : SENT;                 \
    C##2 = (P##2 < n) ? tkP[(size_t)P##2 * TOPK + lane] : SENT;                 \
    C##3 = (P##3 < n) ? tkP[(size_t)P##3 * TOPK + lane] : SENT;                 \
    C##4 = (P##4 < n) ? tkP[(size_t)P##4 * TOPK + lane] : SENT;                 \
    C##5 = (P##5 < n) ? tkP[(size_t)P##5 * TOPK + lane] : SENT;                 \
    C##6 = (P##6 < n) ? tkP[(size_t)P##6 * TOPK + lane] : SENT;                 \
    C##7 = (P##7 < n) ? tkP[(size_t)P##7 * TOPK + lane] : SENT;                 \
} while (0)

#define SETSEL(P, g, v) {                                                       \
    if ((g)==0) P##0=(v); else if ((g)==1) P##1=(v); else if ((g)==2) P##2=(v); \
    else if ((g)==3) P##3=(v); else if ((g)==4) P##4=(v); else if ((g)==5) P##5=(v); \
    else if ((g)==6) P##6=(v); else P##7=(v); }

#define SETBIT(v) { if (lane == (((v) >> 7) & 63)) {                            \
    if ((v) & 64) m1 |= 1ull << ((v) & 63); else m0 |= 1ull << ((v) & 63); } }
#define SETCM(v)  { if (lane == (((v) >> 7) & 63)) {                            \
    if ((v) & 64) cm1 |= 1ull << ((v) & 63); else cm0 |= 1ull << ((v) & 63); } }

#define PH1(P, C, k) unsigned long long vb##k = 0ull; bool rm##k = false;       \
    if (P##k != INFI) {                                                         \
        int r_ = P##k;                                                          \
        unsigned long long rw_ = __shfl((r_ & 64) ? m1 : m0, (r_ >> 7) & 63, 64); \
        rm##k = (rw_ >> (r_ & 63)) & 1ull;                                      \
        int ci_ = (int)C##k.y;                                                  \
        int ow_ = (ci_ >> 7) & 63;                                              \
        unsigned long long w0_ = __shfl(m0, ow_, 64);                           \
        unsigned long long w1_ = __shfl(m1, ow_, 64);                           \
        unsigned long long ws_ = (ci_ & 64) ? w1_ : w0_;                        \
        bool val_ = (ci_ < n) && !((ws_ >> (ci_ & 63)) & 1ull);                 \
        vb##k = __ballot(val_);                                                 \
    }

#define JCOLL(x) ((x)==jj0||(x)==jj1||(x)==jj2||(x)==jj3||(x)==jj4||(x)==jj5||(x)==jj6||(x)==jj7)

#define RES(P, C, k) if (P##k != INFI && !rm##k && !JCOLL(P##k)) {              \
    int r_ = P##k;                                                              \
    unsigned long long w_ = vb##k;                                              \
    int j_ = -1; float v_ = -INFINITY;                                          \
    for (;;) {                                                                  \
        if (!w_) break;                                                         \
        int L_ = __builtin_ctzll(w_);                                           \
        int jc_ = __shfl((int)C##k.y, L_, 64);                                  \
        if (JCOLL(jc_)) { w_ &= w_ - 1; continue; }                             \
        j_ = jc_;                                                               \
        v_ = __uint_as_float((unsigned)__shfl((int)C##k.x, L_, 64));            \
        break;                                                                  \
    }                                                                           \
    if (j_ < 0) {                                                               \
        lm64[lane]      = m0;                                                   \
        lm64[64 + lane] = m1;                                                   \
        if (simOk) {                                                            \
            const float* srow_ = sim + (size_t)r_ * simStride;                  \
            float bv_ = -INFINITY; int bj_ = INFI;                              \
            for (int jb_ = (r_ + 1) & ~63; jb_ < n; jb_ += 64) {                \
                int j2_ = jb_ + lane;                                           \
                unsigned long long wm_ = lm64[((j2_ >> 7) & 63) + ((j2_ & 64) ? 64 : 0)]; \
                bool ok2_ = (j2_ > r_) && (j2_ < n) && !((wm_ >> (j2_ & 63)) & 1ull); \
                float v2_ = ok2_ ? srow_[j2_] : -INFINITY;                      \
                int   i2_ = ok2_ ? j2_ : INFI;                                  \
                if (v2_ > bv_ || (v2_ == bv_ && i2_ < bj_)) { bv_ = v2_; bj_ = i2_; } \
            }                                                                   \
            _Pragma("unroll")                                                   \
            for (int o_ = 1; o_ < 64; o_ <<= 1) {                               \
                float xv_ = __shfl_xor(bv_, o_, 64);                            \
                int   xi_ = __shfl_xor(bj_, o_, 64);                            \
                if (xv_ > bv_ || (xv_ == bv_ && xi_ < bj_)) { bv_ = xv_; bj_ = xi_; } \
            }                                                                   \
            if (bj_ != INFI) { v_ = bv_; j_ = bj_; }                            \
        } else {                                                                \
            exact_fallback(r_, n, lane, E, norms, lm64, v_, j_);                \
            if (j_ == INFI) j_ = -1;                                            \
        }                                                                       \
    }                                                                           \
    bool ok_ = (j_ >= 0) && (v_ >= THRESH);                                     \
    if (ok_) {                                                                  \
        SETBIT(r_); SETBIT(j_); SETCM(j_);                                      \
        jj##k = j_;                                                             \
        if (lane == 0) partner[r_] = j_;                                        \
    } else {                                                                    \
        if (lane == 0) partner[r_] = -1;                                        \
    }                                                                           \
}

    DECL8(ra, ca)
    DECL8(rb, cb)

    BUILD(ra, ca);
    int guard = NMAX + 8;
    while (ra0 != INFI && guard-- > 0) {
        BUILD(rb, cb);          // loads for next batch in flight during resolve
        {
            PH1(ra, ca, 0) PH1(ra, ca, 1) PH1(ra, ca, 2) PH1(ra, ca, 3)
            PH1(ra, ca, 4) PH1(ra, ca, 5) PH1(ra, ca, 6) PH1(ra, ca, 7)
            int jj0=-1,jj1=-1,jj2=-1,jj3=-1,jj4=-1,jj5=-1,jj6=-1,jj7=-1;
            RES(ra, ca, 0) RES(ra, ca, 1) RES(ra, ca, 2) RES(ra, ca, 3)
            RES(ra, ca, 4) RES(ra, ca, 5) RES(ra, ca, 6) RES(ra, ca, 7)
        }
        ra0=rb0; ra1=rb1; ra2=rb2; ra3=rb3; ra4=rb4; ra5=rb5; ra6=rb6; ra7=rb7;
        ca0=cb0; ca1=cb1; ca2=cb2; ca3=cb3; ca4=cb4; ca5=cb5; ca6=cb6; ca7=cb7;
    }

    // fused survivor compaction: survivors = rows not consumed-as-j
    {
        int base = lane << 7;
        unsigned long long s0 = ~cm0, s1 = ~cm1;
        int kn = n - base;
        if (kn <= 0) { s0 = 0ull; s1 = 0ull; }
        else if (kn < 64) { s0 &= (~0ull) >> (64 - kn); s1 = 0ull; }
        else if (kn < 128) { s1 = (kn == 64) ? 0ull : (s1 & ((~0ull) >> (128 - kn))); }
        int cnt = __builtin_popcountll(s0) + __builtin_popcountll(s1);
        int inc = cnt;
        #pragma unroll
        for (int o = 1; o < 64; o <<= 1) {
            int t = __shfl_up(inc, o, 64);
            if (lane >= o) inc += t;
        }
        int p = inc - cnt;
        while (s0) { int b = __builtin_ctzll(s0); s0 &= s0 - 1; srcIdx[p++] = base + b; }
        while (s1) { int b = __builtin_ctzll(s1); s1 &= s1 - 1; srcIdx[p++] = base + 64 + b; }
        if (lane == 63) *dn = inc;
    }
#undef DECL8
#undef BUILD
#undef SETSEL
#undef SETBIT
#undef SETCM
#undef PH1
#undef JCOLL
#undef RES
}

// fused[i] = partner>=0 ? min(e_i + e_p, 1) : e_i ; compact into nxt
__global__ void k_fuse(const float* __restrict__ cur, float* __restrict__ nxt,
                       const int* __restrict__ srcIdx, const int* __restrict__ partner,
                       const int* __restrict__ dn) {
    int nn = *dn;
    int k = blockIdx.x;
    if (k >= nn) return;
    int t = threadIdx.x;     // 0..127
    int i = srcIdx[k];
    int p = partner[i];
    float4 v = ((const float4*)(cur + (size_t)i * D))[t];
    if (p >= 0) {
        float4 w = ((const float4*)(cur + (size_t)p * D))[t];
        v.x = fminf(v.x + w.x, 1.0f);
        v.y = fminf(v.y + w.y, 1.0f);
        v.z = fminf(v.z + w.z, 1.0f);
        v.w = fminf(v.w + w.w, 1.0f);
    }
    ((float4*)(nxt + (size_t)k * D))[t] = v;
}

__global__ void k_copyout(const float* __restrict__ src, float* __restrict__ dst, int nelem) {
    int i = blockIdx.x * 256 + threadIdx.x;
    if (i < nelem) dst[i] = src[i];
}

extern "C" void kernel_launch(void* const* d_in, const int* in_sizes, int n_in,
                              void* d_out, int out_size, void* d_ws, size_t ws_size,
                              hipStream_t stream) {
    const float* input = (const float*)d_in[0];
    const int N0 = in_sizes[0] / D;   // 8192
    char* ws = (char*)d_ws;

    const size_t embA = (size_t)(N0 / 2) * D * sizeof(float);    // 8 MB
    const size_t embB = (size_t)(N0 / 4) * D * sizeof(float);    // 4 MB
    const size_t embH = (size_t)N0 * D * sizeof(unsigned short); // 8 MB
    float* bufA = (float*)ws;
    float* bufB = (float*)(ws + embA);
    unsigned short* curh = (unsigned short*)(ws + embA + embB);
    char* aux = ws + embA + embB + embH;
    float* norms   = (float*)(aux);
    int*   partner = (int*)(aux + 32 * 1024);
    int*   srcIdx  = (int*)(aux + 96 * 1024);
    int*   dn      = (int*)(aux + 128 * 1024);
    int*   needFix = (int*)(aux + 160 * 1024);
    uint2* tkP     = (uint2*)(aux + 256 * 1024);
    float* simTile = (float*)(aux + 256 * 1024 + (size_t)NMAX * TOPK * 8);
    const size_t fixedBytes = embA + embB + embH + 256 * 1024 + (size_t)NMAX * TOPK * 8;

    int TR = NMAX;
    while (TR > 128 && fixedBytes + (size_t)TR * N0 * sizeof(float) > ws_size) TR >>= 1;
    int simOk = (TR == N0) ? 1 : 0;

    const int ROUNDS = 16;
    k_init<<<1, 1, 0, stream>>>(dn, N0);
    for (int r = 0; r < ROUNDS; ++r) {
        const float* cur = (r == 0) ? input : ((r & 1) ? bufA : bufB);
        float* nxt = (r & 1) ? bufB : bufA;
        k_prep<<<N0, 128, 0, stream>>>(cur, norms, curh, dn);
        int NT = N0 / TR;
        for (int t = 0; t < NT; ++t) {
            dim3 g(N0 / 128, TR / 128);
            k_mfma_sim<<<g, 256, 0, stream>>>(curh, norms, simTile, t * TR, TR, N0, dn);
            k_topk<<<TR, 64, 0, stream>>>(simTile, t * TR, TR, N0, tkP, needFix, dn);
            k_topkfix<<<TR, 64, 0, stream>>>(simTile, t * TR, TR, N0, tkP, needFix, dn);
        }
        k_scan6<<<1, 64, 0, stream>>>(tkP, cur, norms, simTile, N0, simOk, partner, srcIdx, dn);
        k_fuse<<<N0, 128, 0, stream>>>(cur, nxt, srcIdx, partner, dn);
    }
    float* fin = bufB;   // ROUNDS-1 = 15 is odd -> last write went to bufB
    k_copyout<<<(out_size + 255) / 256, 256, 0, stream>>>(fin, (float*)d_out, out_size);
}

// Round 8
// 16347.624 us; speedup vs baseline: 1.0675x; 1.0675x over previous
//
#include <hip/hip_runtime.h>
#include <math.h>

#define D 512
#define THRESH 0.5f
#define NMAX 8192
#define TOPK 64
#define INFI 0x7fffffff

typedef short bhalf8 __attribute__((ext_vector_type(8)));
typedef float f32x4 __attribute__((ext_vector_type(4)));

__device__ __forceinline__ unsigned long long rdl64(unsigned long long x, int l) {
    unsigned lo = (unsigned)__builtin_amdgcn_readlane((int)(unsigned)(x & 0xffffffffull), l);
    unsigned hi = (unsigned)__builtin_amdgcn_readlane((int)(unsigned)(x >> 32), l);
    return ((unsigned long long)hi << 32) | lo;
}

__global__ void k_init(int* dn, int n) { *dn = n; }

// fused: norms + fp32->bf16 (RNE). One block (128 thr) per row.
__global__ void k_prep(const float* __restrict__ E, float* __restrict__ norms,
                       unsigned short* __restrict__ H, const int* __restrict__ dn) {
    int n = *dn;
    int row = blockIdx.x;
    if (row >= n) return;
    int t = threadIdx.x; // 0..127
    float4 v = ((const float4*)(E + (size_t)row * D))[t];
    float s = v.x * v.x + v.y * v.y + v.z * v.z + v.w * v.w;
    #pragma unroll
    for (int o = 32; o > 0; o >>= 1) s += __shfl_down(s, o, 64);
    __shared__ float ls[2];
    if ((t & 63) == 0) ls[t >> 6] = s;
    float f[4] = {v.x, v.y, v.z, v.w};
    unsigned short r[4];
    #pragma unroll
    for (int u = 0; u < 4; ++u) {
        unsigned int b = __float_as_uint(f[u]);
        r[u] = (unsigned short)((b + 0x7FFFu + ((b >> 16) & 1u)) >> 16);
    }
    uint2 packed;
    packed.x = (unsigned)r[0] | ((unsigned)r[1] << 16);
    packed.y = (unsigned)r[2] | ((unsigned)r[3] << 16);
    *(uint2*)(H + (size_t)row * D + t * 4) = packed;
    __syncthreads();
    if (t == 0) norms[row] = fmaxf(sqrtf(ls[0] + ls[1]), 1e-8f);
}

// sim tile via bf16 MFMA: 128x128 block tile, 4 waves (2x2), BK=64, K=512.
#define LDSTRIDE 72
__global__ void __launch_bounds__(256) k_mfma_sim(
    const unsigned short* __restrict__ H, const float* __restrict__ norms,
    float* __restrict__ sim, int tile_start, int TR, int simStride,
    const int* __restrict__ dn)
{
    int n = *dn;
    if (tile_start >= n) return;
    int row0 = tile_start + blockIdx.y * 128;
    int col0 = blockIdx.x * 128;
    if (row0 >= n || col0 >= n) return;
    if (col0 + 128 <= row0 + 1) return;     // triangle skip

    __shared__ unsigned short As[128 * LDSTRIDE];
    __shared__ unsigned short Bs[128 * LDSTRIDE];
    int tid = threadIdx.x;
    int lane = tid & 63;
    int wave = tid >> 6;
    int wr = wave >> 1;
    int wc = wave & 1;
    int krow = lane & 15;
    int kgrp = (lane >> 4) * 8;

    f32x4 acc[4][4];
    #pragma unroll
    for (int m = 0; m < 4; ++m)
        #pragma unroll
        for (int t = 0; t < 4; ++t)
            acc[m][t] = (f32x4){0.f, 0.f, 0.f, 0.f};

    for (int k0 = 0; k0 < D; k0 += 64) {
        #pragma unroll
        for (int it = 0; it < 4; ++it) {
            int c  = tid + it * 256;
            int rr = c >> 3;
            int cc = c & 7;
            uint4 va = make_uint4(0, 0, 0, 0);
            int gra = row0 + rr;
            if (gra < n) va = *(const uint4*)(H + (size_t)gra * D + k0 + cc * 8);
            *(uint4*)&As[rr * LDSTRIDE + cc * 8] = va;
            uint4 vb = make_uint4(0, 0, 0, 0);
            int grb = col0 + rr;
            if (grb < n) vb = *(const uint4*)(H + (size_t)grb * D + k0 + cc * 8);
            *(uint4*)&Bs[rr * LDSTRIDE + cc * 8] = vb;
        }
        __syncthreads();
        #pragma unroll
        for (int kk = 0; kk < 64; kk += 32) {
            bhalf8 a[4], b[4];
            #pragma unroll
            for (int m = 0; m < 4; ++m)
                a[m] = *(const bhalf8*)&As[(wr * 64 + m * 16 + krow) * LDSTRIDE + kk + kgrp];
            #pragma unroll
            for (int t = 0; t < 4; ++t)
                b[t] = *(const bhalf8*)&Bs[(wc * 64 + t * 16 + krow) * LDSTRIDE + kk + kgrp];
            #pragma unroll
            for (int m = 0; m < 4; ++m)
                #pragma unroll
                for (int t = 0; t < 4; ++t)
                    acc[m][t] = __builtin_amdgcn_mfma_f32_16x16x32_bf16(a[m], b[t], acc[m][t], 0, 0, 0);
        }
        __syncthreads();
    }

    int fcol = lane & 15;
    int frow = (lane >> 4) * 4;
    #pragma unroll
    for (int m = 0; m < 4; ++m) {
        #pragma unroll
        for (int t = 0; t < 4; ++t) {
            #pragma unroll
            for (int v = 0; v < 4; ++v) {
                int gr = row0 + wr * 64 + m * 16 + frow + v;
                int gc = col0 + wc * 64 + t * 16 + fcol;
                if (gr < n && gc < n)
                    sim[(size_t)(gr - tile_start) * simStride + gc] =
                        acc[m][t][v] / (norms[gr] * norms[gc]);
            }
        }
    }
}

// per-row exact top-64 (val desc, idx asc) among j>i. One wave per row.
__global__ void __launch_bounds__(64) k_topk(
    const float* __restrict__ sim, int tile_start, int TR, int simStride,
    uint2* __restrict__ tkP, int* __restrict__ needFix,
    const int* __restrict__ dn)
{
    int n = *dn;
    int r = blockIdx.x;
    int i = tile_start + r;
    if (r >= TR || i >= n) return;
    int lane = threadIdx.x;
    const float* srow = sim + (size_t)r * simStride;

    float v[8]; int id[8];
    #pragma unroll
    for (int u = 0; u < 8; ++u) { v[u] = -INFINITY; id[u] = INFI; }
    float ovV = -INFINITY; int ovI = INFI;

    for (int j = i + 1 + lane; j < n; j += 64) {
        float x = srow[j];
        if (x > v[7] || (x == v[7] && j < id[7])) {
            if (v[7] > ovV || (v[7] == ovV && id[7] < ovI)) { ovV = v[7]; ovI = id[7]; }
            int p = 7;
            #pragma unroll
            for (int u = 6; u >= 0; --u) {
                bool mv = (x > v[u]) || (x == v[u] && j < id[u]);
                if (mv) { v[u + 1] = v[u]; id[u + 1] = id[u]; p = u; }
            }
            v[p] = x; id[p] = j;
        } else {
            if (x > ovV || (x == ovV && j < ovI)) { ovV = x; ovI = j; }
        }
    }

    int pos = 0;
    float myV = -INFINITY; int myI = INFI;
    for (int k = 0; k < TOPK; ++k) {
        float hv = (pos < 8) ? v[pos] : -INFINITY;
        int   hi = (pos < 8) ? id[pos] : INFI;
        float bv = hv; int bi = hi;
        #pragma unroll
        for (int o = 1; o < 64; o <<= 1) {
            float xv = __shfl_xor(bv, o, 64);
            int   xi = __shfl_xor(bi, o, 64);
            if (xv > bv || (xv == bv && xi < bi)) { bv = xv; bi = xi; }
        }
        if (pos < 8 && hv == bv && hi == bi) pos++;
        if (k == lane) { myV = bv; myI = bi; }
    }
    tkP[(size_t)i * TOPK + lane] = make_uint2(__float_as_uint(myV), (unsigned)myI);

    float v64 = __shfl(myV, 63, 64);
    int   i64 = __shfl(myI, 63, 64);
    float oV = ovV; int oI = ovI;
    #pragma unroll
    for (int o = 1; o < 64; o <<= 1) {
        float xv = __shfl_xor(oV, o, 64);
        int   xi = __shfl_xor(oI, o, 64);
        if (xv > oV || (xv == oV && xi < oI)) { oV = xv; oI = xi; }
    }
    int bad = (oV > v64) || (oV == v64 && oI < i64);
    if (lane == 0) needFix[i] = bad;
}

// rare exact redo: per-lane top-64 lists in LDS (unconditionally exact)
__global__ void __launch_bounds__(64) k_topkfix(
    const float* __restrict__ sim, int tile_start, int TR, int simStride,
    uint2* __restrict__ tkP, const int* __restrict__ needFix,
    const int* __restrict__ dn)
{
    int n = *dn;
    int r = blockIdx.x;
    int i = tile_start + r;
    if (r >= TR || i >= n) return;
    if (!needFix[i]) return;
    int lane = threadIdx.x;
    __shared__ float lv[64][TOPK];
    __shared__ int   li[64][TOPK];
    for (int u = 0; u < TOPK; ++u) { lv[lane][u] = -INFINITY; li[lane][u] = INFI; }
    const float* srow = sim + (size_t)r * simStride;
    for (int j = i + 1 + lane; j < n; j += 64) {
        float x = srow[j];
        float wv = lv[lane][TOPK - 1]; int wi = li[lane][TOPK - 1];
        if (x > wv || (x == wv && j < wi)) {
            int p = TOPK - 1;
            for (int u = TOPK - 2; u >= 0; --u) {
                float uv = lv[lane][u]; int ui = li[lane][u];
                if (x > uv || (x == uv && j < ui)) { lv[lane][u + 1] = uv; li[lane][u + 1] = ui; p = u; }
                else break;
            }
            lv[lane][p] = x; li[lane][p] = j;
        }
    }
    int pos = 0;
    float myV = -INFINITY; int myI = INFI;
    for (int k = 0; k < TOPK; ++k) {
        float hv = (pos < TOPK) ? lv[lane][pos] : -INFINITY;
        int   hi = (pos < TOPK) ? li[lane][pos] : INFI;
        float bv = hv; int bi = hi;
        #pragma unroll
        for (int o = 1; o < 64; o <<= 1) {
            float xv = __shfl_xor(bv, o, 64);
            int   xi = __shfl_xor(bi, o, 64);
            if (xv > bv || (xv == bv && xi < bi)) { bv = xv; bi = xi; }
        }
        if (pos < TOPK && hv == bv && hi == bi) pos++;
        if (k == lane) { myV = bv; myI = bi; }
    }
    tkP[(size_t)i * TOPK + lane] = make_uint2(__float_as_uint(myV), (unsigned)myI);
}

// dot-product fallback (only if sim matrix not fully resident). Reads lmask.
__device__ __attribute__((noinline)) void dot_fallback(
    int r, int n, int lane, const float* __restrict__ E,
    const float* __restrict__ norms, const unsigned long long* lmask,
    float& obv, int& obj)
{
    float ni = norms[r];
    float4 e0 = *(const float4*)(E + (size_t)r * D + lane * 8);
    float4 e1 = *(const float4*)(E + (size_t)r * D + lane * 8 + 4);
    float bbv = -INFINITY; int bbj = INFI;
    int w0 = (r + 1) >> 6, wN = (n + 63) >> 6;
    for (int ww = w0; ww < wN; ++ww) {
        unsigned long long um = ~lmask[ww];
        if (ww == (r >> 6)) um &= (~0ull) << ((r & 63) + 1);
        int over = (ww << 6) + 64 - n;
        if (over > 0) um &= (over >= 64) ? 0ull : ((~0ull) >> over);
        while (um) {
            int b = __builtin_ctzll(um);
            um &= um - 1;
            int jj = (ww << 6) + b;
            float4 a0 = *(const float4*)(E + (size_t)jj * D + lane * 8);
            float4 a1 = *(const float4*)(E + (size_t)jj * D + lane * 8 + 4);
            float s = e0.x * a0.x + e0.y * a0.y + e0.z * a0.z + e0.w * a0.w
                    + e1.x * a1.x + e1.y * a1.y + e1.z * a1.z + e1.w * a1.w;
            #pragma unroll
            for (int o = 1; o < 64; o <<= 1) s += __shfl_xor(s, o, 64);
            float sv = s / (ni * norms[jj]);
            if (sv > bbv || (sv == bbv && jj < bbj)) { bbv = sv; bbj = jj; }
        }
    }
    obv = bbv; obj = bbj;
}

// greedy scan, one wave. Merged mask lives in LDS (128 u64 words, always
// fresh) + per-owner-lane register copy for BUILD. Per-pop chain:
// ds_read_b64 (per-lane candidate word) -> ballot -> v_readlane -> ds_write.
// Uniform-lane broadcasts via readlane (no bpermute). Batch row-merged
// re-checks are pure-SALU skip bitmasks. Candidate loads one batch ahead.
__global__ void __launch_bounds__(64) k_scan7(
    const uint2* __restrict__ tkP,
    const float* __restrict__ E, const float* __restrict__ norms,
    const float* __restrict__ sim, int simStride, int simOk,
    int* __restrict__ partner, int* __restrict__ srcIdx,
    int* __restrict__ dn)
{
    int n = *dn;
    int lane = threadIdx.x;
    int base_ = lane << 7;

    __shared__ unsigned long long lmask[128];   // word w = bits [w*64,(w+1)*64)
    lmask[lane] = 0ull;
    lmask[64 + lane] = 0ull;
    asm volatile("s_waitcnt lgkmcnt(0)" ::: "memory");

    unsigned long long own0 = 0ull, own1 = 0ull;   // lane's bits [lane*128,+128)
    unsigned long long cm0 = 0ull, cm1 = 0ull;     // consumed-as-j only
    int nextStart = 0;
    unsigned skipA = 0, skipB = 0;
    const uint2 SENT = make_uint2(0xFF800000u, (unsigned)INFI);

#define WINDOW(U0, U1, LO) {                                                   \
    long long kw_ = (long long)(LO) - base_;                                   \
    if (kw_ > 0) {                                                             \
        if (kw_ >= 128) { U0 = 0ull; U1 = 0ull; }                              \
        else if (kw_ >= 64) { U0 = 0ull; if (kw_ > 64) U1 &= (~0ull) << (int)(kw_ - 64); } \
        else U0 &= (~0ull) << (int)kw_;                                        \
    }                                                                          \
    int kn_ = n - base_;                                                       \
    if (kn_ <= 0) { U0 = 0ull; U1 = 0ull; }                                    \
    else if (kn_ < 64) { U0 &= (~0ull) >> (64 - kn_); U1 = 0ull; }             \
    else if (kn_ < 128) { U1 = (kn_ == 64) ? 0ull : (U1 & ((~0ull) >> (128 - kn_))); } }

#define SETSEL(P, g, v) {                                                       \
    if ((g)==0) P##0=(v); else if ((g)==1) P##1=(v); else if ((g)==2) P##2=(v); \
    else if ((g)==3) P##3=(v); else if ((g)==4) P##4=(v); else if ((g)==5) P##5=(v); \
    else if ((g)==6) P##6=(v); else P##7=(v); }

#define BUILD(P, C, SK) do {                                                    \
    P##0=INFI;P##1=INFI;P##2=INFI;P##3=INFI;P##4=INFI;P##5=INFI;P##6=INFI;P##7=INFI; \
    SK = 0;                                                                     \
    unsigned long long u0_ = ~own0, u1_ = ~own1;                                \
    WINDOW(u0_, u1_, nextStart)                                                 \
    unsigned long long balv_ = __ballot((u0_ | u1_) != 0ull);                   \
    int got_ = 0, lastSel_ = -1;                                                \
    while (got_ < 8 && balv_) {                                                 \
        int L_ = (int)__builtin_ctzll(balv_); balv_ &= balv_ - 1;               \
        unsigned long long w0_ = rdl64(u0_, L_);                                \
        unsigned long long w1_ = rdl64(u1_, L_);                                \
        int bs_ = L_ << 7;                                                      \
        while (w0_ && got_ < 8) { int b_ = (int)__builtin_ctzll(w0_); w0_ &= w0_-1; \
            int v_ = bs_ + b_; lastSel_ = v_; SETSEL(P, got_, v_); got_++; }    \
        while (w1_ && got_ < 8) { int b_ = (int)__builtin_ctzll(w1_); w1_ &= w1_-1; \
            int v_ = bs_ + 64 + b_; lastSel_ = v_; SETSEL(P, got_, v_); got_++; } \
    }                                                                           \
    nextStart = (got_ > 0) ? (lastSel_ + 1) : n;                                \
    C##0 = (P##0 < n) ? tkP[(size_t)P##0 * TOPK + lane] : SENT;                 \
    C##1 = (P##1 < n) ? tkP[(size_t)P##1 * TOPK + lane] : SENT;                 \
    C##2 = (P##2 < n) ? tkP[(size_t)P##2 * TOPK + lane] : SENT;                 \
    C##3 = (P##3 < n) ? tkP[(size_t)P##3 * TOPK + lane] : SENT;                 \
    C##4 = (P##4 < n) ? tkP[(size_t)P##4 * TOPK + lane] : SENT;                 \
    C##5 = (P##5 < n) ? tkP[(size_t)P##5 * TOPK + lane] : SENT;                 \
    C##6 = (P##6 < n) ? tkP[(size_t)P##6 * TOPK + lane] : SENT;                 \
    C##7 = (P##7 < n) ? tkP[(size_t)P##7 * TOPK + lane] : SENT;                 \
} while (0)

// set merged bit for uniform index v in register copy + LDS
#define SETBIT(v) { if (lane == ((v) >> 7)) {                                   \
    if (((v) >> 6) & 1) { own1 |= 1ull << ((v) & 63); lmask[2*lane+1] = own1; } \
    else                { own0 |= 1ull << ((v) & 63); lmask[2*lane]   = own0; } } }
#define SETCMB(v) { if (lane == ((v) >> 7)) {                                   \
    if (((v) >> 6) & 1) cm1 |= 1ull << ((v) & 63);                              \
    else                cm0 |= 1ull << ((v) & 63); } }

#define SKIPUPD(jv)                                                             \
    skipA |= ((jv==ra0)?1u:0)|((jv==ra1)?2u:0)|((jv==ra2)?4u:0)|((jv==ra3)?8u:0)   \
           |((jv==ra4)?16u:0)|((jv==ra5)?32u:0)|((jv==ra6)?64u:0)|((jv==ra7)?128u:0); \
    skipB |= ((jv==rb0)?1u:0)|((jv==rb1)?2u:0)|((jv==rb2)?4u:0)|((jv==rb3)?8u:0)   \
           |((jv==rb4)?16u:0)|((jv==rb5)?32u:0)|((jv==rb6)?64u:0)|((jv==rb7)?128u:0);

#define POPSLOT(k) if (ra##k != INFI && !((skipA >> k) & 1u)) {                 \
    int r_ = ra##k;                                                             \
    int ci_ = (int)ca##k.y;                                                     \
    bool okc_ = ci_ < n;                                                        \
    int wi_ = okc_ ? (ci_ >> 6) : 0;                                            \
    unsigned long long wm_ = *(volatile unsigned long long*)&lmask[wi_];        \
    bool valid_ = okc_ && !((wm_ >> (ci_ & 63)) & 1ull);                        \
    unsigned long long bal_ = __ballot(valid_);                                 \
    int j_ = -1; float v_ = -INFINITY;                                          \
    if (bal_) {                                                                 \
        int L_ = (int)__builtin_ctzll(bal_);                                    \
        j_ = __builtin_amdgcn_readlane(ci_, L_);                                \
        v_ = __uint_as_float((unsigned)__builtin_amdgcn_readlane((int)ca##k.x, L_)); \
    } else {                                                                    \
        unsigned long long u0_ = ~own0, u1_ = ~own1;                            \
        WINDOW(u0_, u1_, r_ + 1)                                                \
        if (__ballot((u0_ | u1_) != 0ull)) {                                    \
            if (simOk) {                                                        \
                const float* srow_ = sim + (size_t)r_ * simStride;              \
                float bv_ = -INFINITY; int bj_ = INFI;                          \
                for (int jb_ = (r_ + 1) & ~63; jb_ < n; jb_ += 64) {            \
                    int j2_ = jb_ + lane;                                       \
                    unsigned long long wm2_ = *(volatile unsigned long long*)&lmask[j2_ >> 6]; \
                    bool ok2_ = (j2_ > r_) && (j2_ < n) && !((wm2_ >> (j2_ & 63)) & 1ull); \
                    float v2_ = ok2_ ? srow_[j2_] : -INFINITY;                  \
                    int   i2_ = ok2_ ? j2_ : INFI;                              \
                    if (v2_ > bv_ || (v2_ == bv_ && i2_ < bj_)) { bv_ = v2_; bj_ = i2_; } \
                }                                                               \
                _Pragma("unroll")                                               \
                for (int o_ = 1; o_ < 64; o_ <<= 1) {                           \
                    float xv_ = __shfl_xor(bv_, o_, 64);                        \
                    int   xi_ = __shfl_xor(bj_, o_, 64);                        \
                    if (xv_ > bv_ || (xv_ == bv_ && xi_ < bj_)) { bv_ = xv_; bj_ = xi_; } \
                }                                                               \
                if (bj_ != INFI) { v_ = bv_; j_ = bj_; }                        \
            } else {                                                            \
                dot_fallback(r_, n, lane, E, norms, (const unsigned long long*)lmask, v_, j_); \
                if (j_ == INFI) j_ = -1;                                        \
            }                                                                   \
        }                                                                       \
    }                                                                           \
    bool ok_ = (j_ >= 0) && (v_ >= THRESH);                                     \
    if (ok_) {                                                                  \
        SETBIT(r_); SETBIT(j_); SETCMB(j_);                                     \
        asm volatile("s_waitcnt lgkmcnt(0)" ::: "memory");                      \
        SKIPUPD(j_)                                                             \
        if (lane == 0) partner[r_] = j_;                                        \
    } else {                                                                    \
        if (lane == 0) partner[r_] = -1;                                        \
    }                                                                           \
}

    int ra0,ra1,ra2,ra3,ra4,ra5,ra6,ra7;
    int rb0,rb1,rb2,rb3,rb4,rb5,rb6,rb7;
    uint2 ca0,ca1,ca2,ca3,ca4,ca5,ca6,ca7;
    uint2 cb0,cb1,cb2,cb3,cb4,cb5,cb6,cb7;

    BUILD(ra, ca, skipA);
    int guard = NMAX + 8;
    while (ra0 != INFI && guard-- > 0) {
        BUILD(rb, cb, skipB);       // next-batch loads in flight during pops
        POPSLOT(0) POPSLOT(1) POPSLOT(2) POPSLOT(3)
        POPSLOT(4) POPSLOT(5) POPSLOT(6) POPSLOT(7)
        ra0=rb0; ra1=rb1; ra2=rb2; ra3=rb3; ra4=rb4; ra5=rb5; ra6=rb6; ra7=rb7;
        ca0=cb0; ca1=cb1; ca2=cb2; ca3=cb3; ca4=cb4; ca5=cb5; ca6=cb6; ca7=cb7;
        skipA = skipB;
    }

    // fused survivor compaction: survivors = rows not consumed-as-j
    {
        int base = lane << 7;
        unsigned long long s0 = ~cm0, s1 = ~cm1;
        int kn = n - base;
        if (kn <= 0) { s0 = 0ull; s1 = 0ull; }
        else if (kn < 64) { s0 &= (~0ull) >> (64 - kn); s1 = 0ull; }
        else if (kn < 128) { s1 = (kn == 64) ? 0ull : (s1 & ((~0ull) >> (128 - kn))); }
        int cnt = __builtin_popcountll(s0) + __builtin_popcountll(s1);
        int inc = cnt;
        #pragma unroll
        for (int o = 1; o < 64; o <<= 1) {
            int t = __shfl_up(inc, o, 64);
            if (lane >= o) inc += t;
        }
        int p = inc - cnt;
        while (s0) { int b = __builtin_ctzll(s0); s0 &= s0 - 1; srcIdx[p++] = base + b; }
        while (s1) { int b = __builtin_ctzll(s1); s1 &= s1 - 1; srcIdx[p++] = base + 64 + b; }
        if (lane == 63) *dn = inc;
    }
#undef WINDOW
#undef SETSEL
#undef BUILD
#undef SETBIT
#undef SETCMB
#undef SKIPUPD
#undef POPSLOT
}

// fused[i] = partner>=0 ? min(e_i + e_p, 1) : e_i ; compact into nxt
__global__ void k_fuse(const float* __restrict__ cur, float* __restrict__ nxt,
                       const int* __restrict__ srcIdx, const int* __restrict__ partner,
                       const int* __restrict__ dn) {
    int nn = *dn;
    int k = blockIdx.x;
    if (k >= nn) return;
    int t = threadIdx.x;     // 0..127
    int i = srcIdx[k];
    int p = partner[i];
    float4 v = ((const float4*)(cur + (size_t)i * D))[t];
    if (p >= 0) {
        float4 w = ((const float4*)(cur + (size_t)p * D))[t];
        v.x = fminf(v.x + w.x, 1.0f);
        v.y = fminf(v.y + w.y, 1.0f);
        v.z = fminf(v.z + w.z, 1.0f);
        v.w = fminf(v.w + w.w, 1.0f);
    }
    ((float4*)(nxt + (size_t)k * D))[t] = v;
}

__global__ void k_copyout(const float* __restrict__ src, float* __restrict__ dst, int nelem) {
    int i = blockIdx.x * 256 + threadIdx.x;
    if (i < nelem) dst[i] = src[i];
}

extern "C" void kernel_launch(void* const* d_in, const int* in_sizes, int n_in,
                              void* d_out, int out_size, void* d_ws, size_t ws_size,
                              hipStream_t stream) {
    const float* input = (const float*)d_in[0];
    const int N0 = in_sizes[0] / D;   // 8192
    char* ws = (char*)d_ws;

    const size_t embA = (size_t)(N0 / 2) * D * sizeof(float);    // 8 MB
    const size_t embB = (size_t)(N0 / 4) * D * sizeof(float);    // 4 MB
    const size_t embH = (size_t)N0 * D * sizeof(unsigned short); // 8 MB
    float* bufA = (float*)ws;
    float* bufB = (float*)(ws + embA);
    unsigned short* curh = (unsigned short*)(ws + embA + embB);
    char* aux = ws + embA + embB + embH;
    float* norms   = (float*)(aux);
    int*   partner = (int*)(aux + 32 * 1024);
    int*   srcIdx  = (int*)(aux + 96 * 1024);
    int*   dn      = (int*)(aux + 128 * 1024);
    int*   needFix = (int*)(aux + 160 * 1024);
    uint2* tkP     = (uint2*)(aux + 256 * 1024);
    float* simTile = (float*)(aux + 256 * 1024 + (size_t)NMAX * TOPK * 8);
    const size_t fixedBytes = embA + embB + embH + 256 * 1024 + (size_t)NMAX * TOPK * 8;

    int TR = NMAX;
    while (TR > 128 && fixedBytes + (size_t)TR * N0 * sizeof(float) > ws_size) TR >>= 1;
    int simOk = (TR == N0) ? 1 : 0;

    const int ROUNDS = 16;
    k_init<<<1, 1, 0, stream>>>(dn, N0);
    for (int r = 0; r < ROUNDS; ++r) {
        const float* cur = (r == 0) ? input : ((r & 1) ? bufA : bufB);
        float* nxt = (r & 1) ? bufB : bufA;
        k_prep<<<N0, 128, 0, stream>>>(cur, norms, curh, dn);
        int NT = N0 / TR;
        for (int t = 0; t < NT; ++t) {
            dim3 g(N0 / 128, TR / 128);
            k_mfma_sim<<<g, 256, 0, stream>>>(curh, norms, simTile, t * TR, TR, N0, dn);
            k_topk<<<TR, 64, 0, stream>>>(simTile, t * TR, TR, N0, tkP, needFix, dn);
            k_topkfix<<<TR, 64, 0, stream>>>(simTile, t * TR, TR, N0, tkP, needFix, dn);
        }
        k_scan7<<<1, 64, 0, stream>>>(tkP, cur, norms, simTile, N0, simOk, partner, srcIdx, dn);
        k_fuse<<<N0, 128, 0, stream>>>(cur, nxt, srcIdx, partner, dn);
    }
    float* fin = bufB;   // ROUNDS-1 = 15 is odd -> last write went to bufB
    k_copyout<<<(out_size + 255) / 256, 256, 0, stream>>>(fin, (float*)d_out, out_size);
}

// Round 9
// 15607.610 us; speedup vs baseline: 1.1181x; 1.0474x over previous
//
#include <hip/hip_runtime.h>
#include <math.h>

#define D 512
#define THRESH 0.5f
#define NMAX 8192
#define TOPK 64
#define INFI 0x7fffffff

typedef short bhalf8 __attribute__((ext_vector_type(8)));
typedef float f32x4 __attribute__((ext_vector_type(4)));

__device__ __forceinline__ unsigned long long rdl64(unsigned long long x, int l) {
    unsigned lo = (unsigned)__builtin_amdgcn_readlane((int)(unsigned)(x & 0xffffffffull), l);
    unsigned hi = (unsigned)__builtin_amdgcn_readlane((int)(unsigned)(x >> 32), l);
    return ((unsigned long long)hi << 32) | lo;
}

__global__ void k_init(int* dn, int n) { *dn = n; }

// fused: norms + fp32->bf16 (RNE) + partner=-1 init. One block (128 thr)/row.
__global__ void k_prep(const float* __restrict__ E, float* __restrict__ norms,
                       unsigned short* __restrict__ H, int* __restrict__ partner,
                       const int* __restrict__ dn) {
    int n = *dn;
    int row = blockIdx.x;
    if (row >= n) return;
    int t = threadIdx.x; // 0..127
    float4 v = ((const float4*)(E + (size_t)row * D))[t];
    float s = v.x * v.x + v.y * v.y + v.z * v.z + v.w * v.w;
    #pragma unroll
    for (int o = 32; o > 0; o >>= 1) s += __shfl_down(s, o, 64);
    __shared__ float ls[2];
    if ((t & 63) == 0) ls[t >> 6] = s;
    float f[4] = {v.x, v.y, v.z, v.w};
    unsigned short r[4];
    #pragma unroll
    for (int u = 0; u < 4; ++u) {
        unsigned int b = __float_as_uint(f[u]);
        r[u] = (unsigned short)((b + 0x7FFFu + ((b >> 16) & 1u)) >> 16);
    }
    uint2 packed;
    packed.x = (unsigned)r[0] | ((unsigned)r[1] << 16);
    packed.y = (unsigned)r[2] | ((unsigned)r[3] << 16);
    *(uint2*)(H + (size_t)row * D + t * 4) = packed;
    if (t == 64) partner[row] = -1;
    __syncthreads();
    if (t == 0) norms[row] = fmaxf(sqrtf(ls[0] + ls[1]), 1e-8f);
}

// sim tile via bf16 MFMA: 128x128 block tile, 4 waves (2x2), BK=64, K=512.
#define LDSTRIDE 72
__global__ void __launch_bounds__(256) k_mfma_sim(
    const unsigned short* __restrict__ H, const float* __restrict__ norms,
    float* __restrict__ sim, int tile_start, int TR, int simStride,
    const int* __restrict__ dn)
{
    int n = *dn;
    if (tile_start >= n) return;
    int row0 = tile_start + blockIdx.y * 128;
    int col0 = blockIdx.x * 128;
    if (row0 >= n || col0 >= n) return;
    if (col0 + 128 <= row0 + 1) return;     // triangle skip

    __shared__ unsigned short As[128 * LDSTRIDE];
    __shared__ unsigned short Bs[128 * LDSTRIDE];
    int tid = threadIdx.x;
    int lane = tid & 63;
    int wave = tid >> 6;
    int wr = wave >> 1;
    int wc = wave & 1;
    int krow = lane & 15;
    int kgrp = (lane >> 4) * 8;

    f32x4 acc[4][4];
    #pragma unroll
    for (int m = 0; m < 4; ++m)
        #pragma unroll
        for (int t = 0; t < 4; ++t)
            acc[m][t] = (f32x4){0.f, 0.f, 0.f, 0.f};

    for (int k0 = 0; k0 < D; k0 += 64) {
        #pragma unroll
        for (int it = 0; it < 4; ++it) {
            int c  = tid + it * 256;
            int rr = c >> 3;
            int cc = c & 7;
            uint4 va = make_uint4(0, 0, 0, 0);
            int gra = row0 + rr;
            if (gra < n) va = *(const uint4*)(H + (size_t)gra * D + k0 + cc * 8);
            *(uint4*)&As[rr * LDSTRIDE + cc * 8] = va;
            uint4 vb = make_uint4(0, 0, 0, 0);
            int grb = col0 + rr;
            if (grb < n) vb = *(const uint4*)(H + (size_t)grb * D + k0 + cc * 8);
            *(uint4*)&Bs[rr * LDSTRIDE + cc * 8] = vb;
        }
        __syncthreads();
        #pragma unroll
        for (int kk = 0; kk < 64; kk += 32) {
            bhalf8 a[4], b[4];
            #pragma unroll
            for (int m = 0; m < 4; ++m)
                a[m] = *(const bhalf8*)&As[(wr * 64 + m * 16 + krow) * LDSTRIDE + kk + kgrp];
            #pragma unroll
            for (int t = 0; t < 4; ++t)
                b[t] = *(const bhalf8*)&Bs[(wc * 64 + t * 16 + krow) * LDSTRIDE + kk + kgrp];
            #pragma unroll
            for (int m = 0; m < 4; ++m)
                #pragma unroll
                for (int t = 0; t < 4; ++t)
                    acc[m][t] = __builtin_amdgcn_mfma_f32_16x16x32_bf16(a[m], b[t], acc[m][t], 0, 0, 0);
        }
        __syncthreads();
    }

    int fcol = lane & 15;
    int frow = (lane >> 4) * 4;
    #pragma unroll
    for (int m = 0; m < 4; ++m) {
        #pragma unroll
        for (int t = 0; t < 4; ++t) {
            #pragma unroll
            for (int v = 0; v < 4; ++v) {
                int gr = row0 + wr * 64 + m * 16 + frow + v;
                int gc = col0 + wc * 64 + t * 16 + fcol;
                if (gr < n && gc < n)
                    sim[(size_t)(gr - tile_start) * simStride + gc] =
                        acc[m][t][v] / (norms[gr] * norms[gc]);
            }
        }
    }
}

// per-row exact top-64 (val desc, idx asc) among j>i. One wave per row.
__global__ void __launch_bounds__(64) k_topk(
    const float* __restrict__ sim, int tile_start, int TR, int simStride,
    uint2* __restrict__ tkP, int* __restrict__ needFix,
    const int* __restrict__ dn)
{
    int n = *dn;
    int r = blockIdx.x;
    int i = tile_start + r;
    if (r >= TR || i >= n) return;
    int lane = threadIdx.x;
    const float* srow = sim + (size_t)r * simStride;

    float v[8]; int id[8];
    #pragma unroll
    for (int u = 0; u < 8; ++u) { v[u] = -INFINITY; id[u] = INFI; }
    float ovV = -INFINITY; int ovI = INFI;

    for (int j = i + 1 + lane; j < n; j += 64) {
        float x = srow[j];
        if (x > v[7] || (x == v[7] && j < id[7])) {
            if (v[7] > ovV || (v[7] == ovV && id[7] < ovI)) { ovV = v[7]; ovI = id[7]; }
            int p = 7;
            #pragma unroll
            for (int u = 6; u >= 0; --u) {
                bool mv = (x > v[u]) || (x == v[u] && j < id[u]);
                if (mv) { v[u + 1] = v[u]; id[u + 1] = id[u]; p = u; }
            }
            v[p] = x; id[p] = j;
        } else {
            if (x > ovV || (x == ovV && j < ovI)) { ovV = x; ovI = j; }
        }
    }

    int pos = 0;
    float myV = -INFINITY; int myI = INFI;
    for (int k = 0; k < TOPK; ++k) {
        float hv = (pos < 8) ? v[pos] : -INFINITY;
        int   hi = (pos < 8) ? id[pos] : INFI;
        float bv = hv; int bi = hi;
        #pragma unroll
        for (int o = 1; o < 64; o <<= 1) {
            float xv = __shfl_xor(bv, o, 64);
            int   xi = __shfl_xor(bi, o, 64);
            if (xv > bv || (xv == bv && xi < bi)) { bv = xv; bi = xi; }
        }
        if (pos < 8 && hv == bv && hi == bi) pos++;
        if (k == lane) { myV = bv; myI = bi; }
    }
    tkP[(size_t)i * TOPK + lane] = make_uint2(__float_as_uint(myV), (unsigned)myI);

    float v64 = __shfl(myV, 63, 64);
    int   i64 = __shfl(myI, 63, 64);
    float oV = ovV; int oI = ovI;
    #pragma unroll
    for (int o = 1; o < 64; o <<= 1) {
        float xv = __shfl_xor(oV, o, 64);
        int   xi = __shfl_xor(oI, o, 64);
        if (xv > oV || (xv == oV && xi < oI)) { oV = xv; oI = xi; }
    }
    int bad = (oV > v64) || (oV == v64 && oI < i64);
    if (lane == 0) needFix[i] = bad;
}

// rare exact redo: per-lane top-64 lists in LDS (unconditionally exact)
__global__ void __launch_bounds__(64) k_topkfix(
    const float* __restrict__ sim, int tile_start, int TR, int simStride,
    uint2* __restrict__ tkP, const int* __restrict__ needFix,
    const int* __restrict__ dn)
{
    int n = *dn;
    int r = blockIdx.x;
    int i = tile_start + r;
    if (r >= TR || i >= n) return;
    if (!needFix[i]) return;
    int lane = threadIdx.x;
    __shared__ float lv[64][TOPK];
    __shared__ int   li[64][TOPK];
    for (int u = 0; u < TOPK; ++u) { lv[lane][u] = -INFINITY; li[lane][u] = INFI; }
    const float* srow = sim + (size_t)r * simStride;
    for (int j = i + 1 + lane; j < n; j += 64) {
        float x = srow[j];
        float wv = lv[lane][TOPK - 1]; int wi = li[lane][TOPK - 1];
        if (x > wv || (x == wv && j < wi)) {
            int p = TOPK - 1;
            for (int u = TOPK - 2; u >= 0; --u) {
                float uv = lv[lane][u]; int ui = li[lane][u];
                if (x > uv || (x == uv && j < ui)) { lv[lane][u + 1] = uv; li[lane][u + 1] = ui; p = u; }
                else break;
            }
            lv[lane][p] = x; li[lane][p] = j;
        }
    }
    int pos = 0;
    float myV = -INFINITY; int myI = INFI;
    for (int k = 0; k < TOPK; ++k) {
        float hv = (pos < TOPK) ? lv[lane][pos] : -INFINITY;
        int   hi = (pos < TOPK) ? li[lane][pos] : INFI;
        float bv = hv; int bi = hi;
        #pragma unroll
        for (int o = 1; o < 64; o <<= 1) {
            float xv = __shfl_xor(bv, o, 64);
            int   xi = __shfl_xor(bi, o, 64);
            if (xv > bv || (xv == bv && xi < bi)) { bv = xv; bi = xi; }
        }
        if (pos < TOPK && hv == bv && hi == bi) pos++;
        if (k == lane) { myV = bv; myI = bi; }
    }
    tkP[(size_t)i * TOPK + lane] = make_uint2(__float_as_uint(myV), (unsigned)myI);
}

// fallback: masked lex-argmax over precomputed sim row (sim resident)
__device__ __attribute__((noinline)) void sim_fallback(
    int r, int n, int lane, const float* __restrict__ sim, int simStride,
    const volatile unsigned long long* lmask, float& obv, int& obj)
{
    const float* srow = sim + (size_t)r * simStride;
    float bv = -INFINITY; int bj = INFI;
    for (int jb = (r + 1) & ~63; jb < n; jb += 64) {
        int j2 = jb + lane;
        unsigned long long wm = lmask[j2 >> 6];
        bool ok2 = (j2 > r) && (j2 < n) && !((wm >> (j2 & 63)) & 1ull);
        float v2 = ok2 ? srow[j2] : -INFINITY;
        int   i2 = ok2 ? j2 : INFI;
        if (v2 > bv || (v2 == bv && i2 < bj)) { bv = v2; bj = i2; }
    }
    #pragma unroll
    for (int o = 1; o < 64; o <<= 1) {
        float xv = __shfl_xor(bv, o, 64);
        int   xi = __shfl_xor(bj, o, 64);
        if (xv > bv || (xv == bv && xi < bj)) { bv = xv; bj = xi; }
    }
    obv = bv; obj = bj;
}

// dot-product fallback (only if sim matrix not fully resident)
__device__ __attribute__((noinline)) void dot_fallback(
    int r, int n, int lane, const float* __restrict__ E,
    const float* __restrict__ norms, const volatile unsigned long long* lmask,
    float& obv, int& obj)
{
    float ni = norms[r];
    float4 e0 = *(const float4*)(E + (size_t)r * D + lane * 8);
    float4 e1 = *(const float4*)(E + (size_t)r * D + lane * 8 + 4);
    float bbv = -INFINITY; int bbj = INFI;
    int w0 = (r + 1) >> 6, wN = (n + 63) >> 6;
    for (int ww = w0; ww < wN; ++ww) {
        unsigned long long um = ~lmask[ww];
        if (ww == (r >> 6)) um &= (~0ull) << ((r & 63) + 1);
        int over = (ww << 6) + 64 - n;
        if (over > 0) um &= (over >= 64) ? 0ull : ((~0ull) >> over);
        while (um) {
            int b = __builtin_ctzll(um);
            um &= um - 1;
            int jj = (ww << 6) + b;
            float4 a0 = *(const float4*)(E + (size_t)jj * D + lane * 8);
            float4 a1 = *(const float4*)(E + (size_t)jj * D + lane * 8 + 4);
            float s = e0.x * a0.x + e0.y * a0.y + e0.z * a0.z + e0.w * a0.w
                    + e1.x * a1.x + e1.y * a1.y + e1.z * a1.z + e1.w * a1.w;
            #pragma unroll
            for (int o = 1; o < 64; o <<= 1) s += __shfl_xor(s, o, 64);
            float sv = s / (ni * norms[jj]);
            if (sv > bbv || (sv == bbv && jj < bbj)) { bbv = sv; bbj = jj; }
        }
    }
    obv = bbv; obj = bbj;
}

// greedy scan, one wave, chunk-of-16 resolution.
// Per chunk: batched fresh mask checks + 16 validity ballots (LDS, pipelined),
// next-chunk candidate loads issued before resolution (latency hidden),
// then 16 serial commits whose updates are PURE VALU/SALU:
//   ball[m2] &= ~__ballot(cand[m2].idx == j)   (no LDS, no shuffles)
// Candidates of row m are all > m > earlier leaders, so leader-collisions
// are structurally impossible; only j-collisions need updates.
__global__ void __launch_bounds__(64) k_scan8(
    const uint2* __restrict__ tkP,
    const float* __restrict__ E, const float* __restrict__ norms,
    const float* __restrict__ sim, int simStride, int simOk,
    int* __restrict__ partner, int* __restrict__ srcIdx,
    int* __restrict__ dn)
{
    int n = *dn;
    int lane = threadIdx.x;
    int base_ = lane << 7;

    __shared__ unsigned long long lmask[128];   // word w = bits [w*64,(w+1)*64)
    lmask[lane] = 0ull;
    lmask[64 + lane] = 0ull;
    asm volatile("s_waitcnt lgkmcnt(0)" ::: "memory");

    unsigned long long own0 = 0ull, own1 = 0ull;   // lane's bits [lane*128,+128)
    unsigned long long cm0 = 0ull, cm1 = 0ull;     // consumed-as-j only
    int nextStart = 0;
    const uint2 SENT = make_uint2(0xFF800000u, (unsigned)INFI);

#define WINDOW(U0, U1, LO) {                                                   \
    long long kw_ = (long long)(LO) - base_;                                   \
    if (kw_ > 0) {                                                             \
        if (kw_ >= 128) { U0 = 0ull; U1 = 0ull; }                              \
        else if (kw_ >= 64) { U0 = 0ull; if (kw_ > 64) U1 &= (~0ull) << (int)(kw_ - 64); } \
        else U0 &= (~0ull) << (int)kw_;                                        \
    }                                                                          \
    int kn_ = n - base_;                                                       \
    if (kn_ <= 0) { U0 = 0ull; U1 = 0ull; }                                    \
    else if (kn_ < 64) { U0 &= (~0ull) >> (64 - kn_); U1 = 0ull; }             \
    else if (kn_ < 128) { U1 = (kn_ == 64) ? 0ull : (U1 & ((~0ull) >> (128 - kn_))); } }

// row m (compile-time m) from packed 4x u64 (16 bits each, 0xffff = empty)
#define ROWP(R0, R1, R2, R3, m) ((int)((((m) < 4 ? (R0) : (m) < 8 ? (R1) : (m) < 12 ? (R2) : (R3)) >> (((m) & 3) * 16)) & 0xffffull))

#define PUT16(R0, R1, R2, R3, g, v) {                                           \
    unsigned long long vv_ = ((unsigned long long)(unsigned)(v)) << (((g) & 3) * 16); \
    unsigned long long mm_ = 0xffffull << (((g) & 3) * 16);                     \
    if ((g) < 4) R0 = (R0 & ~mm_) | vv_;                                        \
    else if ((g) < 8) R1 = (R1 & ~mm_) | vv_;                                   \
    else if ((g) < 12) R2 = (R2 & ~mm_) | vv_;                                  \
    else R3 = (R3 & ~mm_) | vv_; }

#define BUILD16(R0, R1, R2, R3, CAND) do {                                      \
    R0 = ~0ull; R1 = ~0ull; R2 = ~0ull; R3 = ~0ull;                             \
    unsigned long long u0_ = ~own0, u1_ = ~own1;                                \
    WINDOW(u0_, u1_, nextStart)                                                 \
    unsigned long long balv_ = __ballot((u0_ | u1_) != 0ull);                   \
    int got_ = 0, lastSel_ = -1;                                                \
    while (got_ < 16 && balv_) {                                                \
        int L_ = (int)__builtin_ctzll(balv_); balv_ &= balv_ - 1;               \
        unsigned long long w0_ = rdl64(u0_, L_);                                \
        unsigned long long w1_ = rdl64(u1_, L_);                                \
        int bs_ = L_ << 7;                                                      \
        while (w0_ && got_ < 16) { int b_ = (int)__builtin_ctzll(w0_); w0_ &= w0_ - 1; \
            int v_ = bs_ + b_; PUT16(R0, R1, R2, R3, got_, v_); lastSel_ = v_; got_++; } \
        while (w1_ && got_ < 16) { int b_ = (int)__builtin_ctzll(w1_); w1_ &= w1_ - 1; \
            int v_ = bs_ + 64 + b_; PUT16(R0, R1, R2, R3, got_, v_); lastSel_ = v_; got_++; } \
    }                                                                           \
    nextStart = (got_ > 0) ? (lastSel_ + 1) : n;                                \
    _Pragma("unroll")                                                           \
    for (int m_ = 0; m_ < 16; ++m_) {                                           \
        int rm_ = ROWP(R0, R1, R2, R3, m_);                                     \
        CAND[m_] = (rm_ < n) ? tkP[(size_t)rm_ * TOPK + lane] : SENT;           \
    }                                                                           \
} while (0)

#define SETBIT(v) { if (lane == ((v) >> 7)) {                                   \
    if (((v) >> 6) & 1) { own1 |= 1ull << ((v) & 63); lmask[2*lane+1] = own1; } \
    else                { own0 |= 1ull << ((v) & 63); lmask[2*lane]   = own0; } } }
#define SETCMB(v) { if (lane == ((v) >> 7)) {                                   \
    if (((v) >> 6) & 1) cm1 |= 1ull << ((v) & 63);                              \
    else                cm0 |= 1ull << ((v) & 63); } }

    unsigned long long rpA0, rpA1, rpA2, rpA3, rpB0, rpB1, rpB2, rpB3;
    uint2 candA[16], candB[16];

    BUILD16(rpA0, rpA1, rpA2, rpA3, candA);
    int guard = NMAX + 8;
    while ((int)(rpA0 & 0xffffull) != 0xffff && guard-- > 0) {
        asm volatile("s_waitcnt lgkmcnt(0)" ::: "memory");
        // fresh row-merged checks (uniform broadcast LDS reads)
        unsigned act = 0;
        #pragma unroll
        for (int m = 0; m < 16; ++m) {
            int rm = ROWP(rpA0, rpA1, rpA2, rpA3, m);
            if (rm < n) {
                unsigned long long w = *(volatile unsigned long long*)&lmask[rm >> 6];
                if (!((w >> (rm & 63)) & 1ull)) act |= 1u << m;
            }
        }
        // validity ballots (per-lane LDS reads, independent -> pipelined)
        unsigned long long ball[16];
        #pragma unroll
        for (int m = 0; m < 16; ++m) {
            int ci = (int)candA[m].y;
            bool okc = ci < n;
            unsigned long long w = okc ? *(volatile unsigned long long*)&lmask[ci >> 6] : 0ull;
            bool valid = okc && !((w >> (ci & 63)) & 1ull);
            ball[m] = __ballot(valid);
        }
        // select + issue loads for next chunk (latency hidden under resolve)
        BUILD16(rpB0, rpB1, rpB2, rpB3, candB);
        // serial resolve, pure VALU/SALU per commit
        #pragma unroll
        for (int m = 0; m < 16; ++m) {
            if (!((act >> m) & 1u)) continue;
            int r_ = ROWP(rpA0, rpA1, rpA2, rpA3, m);
            unsigned long long b_ = ball[m];
            int j_ = -1; float v_ = -INFINITY;
            if (b_) {
                int L_ = (int)__builtin_ctzll(b_);
                j_ = __builtin_amdgcn_readlane((int)candA[m].y, L_);
                v_ = __uint_as_float((unsigned)__builtin_amdgcn_readlane((int)candA[m].x, L_));
            } else {
                unsigned long long u0_ = ~own0, u1_ = ~own1;
                WINDOW(u0_, u1_, r_ + 1)
                if (__ballot((u0_ | u1_) != 0ull)) {
                    asm volatile("s_waitcnt lgkmcnt(0)" ::: "memory");
                    if (simOk) sim_fallback(r_, n, lane, sim, simStride,
                                            (const volatile unsigned long long*)lmask, v_, j_);
                    else       dot_fallback(r_, n, lane, E, norms,
                                            (const volatile unsigned long long*)lmask, v_, j_);
                    if (j_ == INFI) j_ = -1;
                }
            }
            if (j_ >= 0 && v_ >= THRESH) {
                SETBIT(r_); SETBIT(j_); SETCMB(j_);
                if (lane == 0) partner[r_] = j_;
                #pragma unroll
                for (int m2 = 0; m2 < 16; ++m2) if (m2 > m) {
                    ball[m2] &= ~__ballot((int)candA[m2].y == j_);
                    if (ROWP(rpA0, rpA1, rpA2, rpA3, m2) == j_) act &= ~(1u << m2);
                }
            }
        }
        // swap B -> A
        rpA0 = rpB0; rpA1 = rpB1; rpA2 = rpB2; rpA3 = rpB3;
        #pragma unroll
        for (int m = 0; m < 16; ++m) candA[m] = candB[m];
    }

    // fused survivor compaction: survivors = rows not consumed-as-j
    {
        int base = lane << 7;
        unsigned long long s0 = ~cm0, s1 = ~cm1;
        int kn = n - base;
        if (kn <= 0) { s0 = 0ull; s1 = 0ull; }
        else if (kn < 64) { s0 &= (~0ull) >> (64 - kn); s1 = 0ull; }
        else if (kn < 128) { s1 = (kn == 64) ? 0ull : (s1 & ((~0ull) >> (128 - kn))); }
        int cnt = __builtin_popcountll(s0) + __builtin_popcountll(s1);
        int inc = cnt;
        #pragma unroll
        for (int o = 1; o < 64; o <<= 1) {
            int t = __shfl_up(inc, o, 64);
            if (lane >= o) inc += t;
        }
        int p = inc - cnt;
        while (s0) { int b = __builtin_ctzll(s0); s0 &= s0 - 1; srcIdx[p++] = base + b; }
        while (s1) { int b = __builtin_ctzll(s1); s1 &= s1 - 1; srcIdx[p++] = base + 64 + b; }
        if (lane == 63) *dn = inc;
    }
#undef WINDOW
#undef ROWP
#undef PUT16
#undef BUILD16
#undef SETBIT
#undef SETCMB
}

// fused[i] = partner>=0 ? min(e_i + e_p, 1) : e_i ; compact into nxt
__global__ void k_fuse(const float* __restrict__ cur, float* __restrict__ nxt,
                       const int* __restrict__ srcIdx, const int* __restrict__ partner,
                       const int* __restrict__ dn) {
    int nn = *dn;
    int k = blockIdx.x;
    if (k >= nn) return;
    int t = threadIdx.x;     // 0..127
    int i = srcIdx[k];
    int p = partner[i];
    float4 v = ((const float4*)(cur + (size_t)i * D))[t];
    if (p >= 0) {
        float4 w = ((const float4*)(cur + (size_t)p * D))[t];
        v.x = fminf(v.x + w.x, 1.0f);
        v.y = fminf(v.y + w.y, 1.0f);
        v.z = fminf(v.z + w.z, 1.0f);
        v.w = fminf(v.w + w.w, 1.0f);
    }
    ((float4*)(nxt + (size_t)k * D))[t] = v;
}

__global__ void k_copyout(const float* __restrict__ src, float* __restrict__ dst, int nelem) {
    int i = blockIdx.x * 256 + threadIdx.x;
    if (i < nelem) dst[i] = src[i];
}

extern "C" void kernel_launch(void* const* d_in, const int* in_sizes, int n_in,
                              void* d_out, int out_size, void* d_ws, size_t ws_size,
                              hipStream_t stream) {
    const float* input = (const float*)d_in[0];
    const int N0 = in_sizes[0] / D;   // 8192
    char* ws = (char*)d_ws;

    const size_t embA = (size_t)(N0 / 2) * D * sizeof(float);    // 8 MB
    const size_t embB = (size_t)(N0 / 4) * D * sizeof(float);    // 4 MB
    const size_t embH = (size_t)N0 * D * sizeof(unsigned short); // 8 MB
    float* bufA = (float*)ws;
    float* bufB = (float*)(ws + embA);
    unsigned short* curh = (unsigned short*)(ws + embA + embB);
    char* aux = ws + embA + embB + embH;
    float* norms   = (float*)(aux);
    int*   partner = (int*)(aux + 32 * 1024);
    int*   srcIdx  = (int*)(aux + 96 * 1024);
    int*   dn      = (int*)(aux + 128 * 1024);
    int*   needFix = (int*)(aux + 160 * 1024);
    uint2* tkP     = (uint2*)(aux + 256 * 1024);
    float* simTile = (float*)(aux + 256 * 1024 + (size_t)NMAX * TOPK * 8);
    const size_t fixedBytes = embA + embB + embH + 256 * 1024 + (size_t)NMAX * TOPK * 8;

    int TR = NMAX;
    while (TR > 128 && fixedBytes + (size_t)TR * N0 * sizeof(float) > ws_size) TR >>= 1;
    int simOk = (TR == N0) ? 1 : 0;

    const int ROUNDS = 16;
    k_init<<<1, 1, 0, stream>>>(dn, N0);
    for (int r = 0; r < ROUNDS; ++r) {
        const float* cur = (r == 0) ? input : ((r & 1) ? bufA : bufB);
        float* nxt = (r & 1) ? bufB : bufA;
        k_prep<<<N0, 128, 0, stream>>>(cur, norms, curh, partner, dn);
        int NT = N0 / TR;
        for (int t = 0; t < NT; ++t) {
            dim3 g(N0 / 128, TR / 128);
            k_mfma_sim<<<g, 256, 0, stream>>>(curh, norms, simTile, t * TR, TR, N0, dn);
            k_topk<<<TR, 64, 0, stream>>>(simTile, t * TR, TR, N0, tkP, needFix, dn);
            k_topkfix<<<TR, 64, 0, stream>>>(simTile, t * TR, TR, N0, tkP, needFix, dn);
        }
        k_scan8<<<1, 64, 0, stream>>>(tkP, cur, norms, simTile, N0, simOk, partner, srcIdx, dn);
        k_fuse<<<N0, 128, 0, stream>>>(cur, nxt, srcIdx, partner, dn);
    }
    float* fin = bufB;   // ROUNDS-1 = 15 is odd -> last write went to bufB
    k_copyout<<<(out_size + 255) / 256, 256, 0, stream>>>(fin, (float*)d_out, out_size);
}